// Round 2
// baseline (419.375 us; speedup 1.0000x reference)
//
#include <hip/hip_runtime.h>
#include <hip/hip_bf16.h>
#include <stdint.h>

#define DIM 768
#define HID 3072
#define NE 8
#define NTOK 4096
#define PADROWS 5120   // padded slot space (per-expert 128-aligned segments)
#define MAXT 40        // max M-tiles: sum ceil(Ne/128) <= 39

// meta (int) layout inside ws
#define M_PO 0
#define M_NTILES 24
#define M_TE 25
#define M_TR 65
#define M_TV 105
#define M_PERM 256
#define XE_OFF (64 * 1024)
#define H_OFF  8126464         // XE_OFF + 5248*768*2

typedef short short8 __attribute__((ext_vector_type(8)));
typedef short short4v __attribute__((ext_vector_type(4)));
typedef float f32x4 __attribute__((ext_vector_type(4)));

// fp32 -> bf16 RNE via hardware (v_cvt_pk_bf16_f32 when paired by compiler)
__device__ __forceinline__ short bfs(float f) {
  __hip_bfloat16 h = __float2bfloat16(f);
  short s; __builtin_memcpy(&s, &h, 2); return s;
}

// ---------------- routing ----------------
__global__ void route_kernel(const int* __restrict__ map, int* __restrict__ meta) {
  __shared__ int scnt[NE];
  __shared__ int scur[NE];
  int t = threadIdx.x;
  if (t < NE) scnt[t] = 0;
  __syncthreads();
  for (int i = t; i < NTOK; i += 256) atomicAdd(&scnt[map[i]], 1);
  __syncthreads();
  if (t == 0) {
    int acc = 0, nt = 0;
    for (int e = 0; e < NE; ++e) {
      meta[M_PO + e] = acc;
      scur[e] = acc;
      int c = scnt[e];
      for (int r = 0; r < c; r += 128) {
        meta[M_TE + nt] = e;
        meta[M_TR + nt] = acc + r;
        meta[M_TV + nt] = (c - r < 128) ? (c - r) : 128;
        ++nt;
      }
      acc += (c + 127) & ~127;
    }
    meta[M_PO + 8] = acc;
    meta[M_NTILES] = nt;
  }
  for (int i = t; i < PADROWS; i += 256) meta[M_PERM + i] = 0;  // safe token for pads
  __syncthreads();
  for (int i = t; i < NTOK; i += 256) {
    int e = map[i];
    int slot = atomicAdd(&scur[e], 1);
    meta[M_PERM + slot] = i;
  }
}

// ------------- gather x -> Xe (bf16, expert-contiguous, pre-swizzled) -------------
__global__ void gather_kernel(const float* __restrict__ x, const int* __restrict__ meta,
                              short* __restrict__ Xe) {
  int id = blockIdx.x * 256 + threadIdx.x;   // 16B-chunk id
  if (id >= PADROWS * 96) return;
  int row = id / 96;
  int sub = id - row * 96;                    // 96 chunks of 8 cols per row
  int tok = meta[M_PERM + row];
  const float* src = x + (size_t)tok * DIM + sub * 8;
  float4 a = *(const float4*)src;
  float4 b = *(const float4*)(src + 4);
  short8 v;
  v[0] = bfs(a.x); v[1] = bfs(a.y); v[2] = bfs(a.z); v[3] = bfs(a.w);
  v[4] = bfs(b.x); v[5] = bfs(b.y); v[6] = bfs(b.z); v[7] = bfs(b.w);
  int blk = sub >> 3, s = sub & 7;
  int off = row * (DIM * 2) + blk * 128 + ((s * 16) ^ ((row & 7) << 4));
  *(short8*)((char*)Xe + off) = v;
}

// B reg->LDS transpose+cvt writers. kb fast (tid&15) => dense global reads
// (16 rows x 64B segments) and uniform 4 words/bank LDS writes (no excess conflict).
__device__ __forceinline__ void write_bt2(char* bt0, char* bt1,
                                          const float4 (&br)[2][4], int kb, int jb) {
  char* bts[2] = {bt0, bt1};
  #pragma unroll
  for (int mat = 0; mat < 2; ++mat) {
    #pragma unroll
    for (int i = 0; i < 4; ++i) {
      int c2 = jb * 4 + i;
      short4v s;
      s[0] = bfs(((const float*)&br[mat][0])[i]);
      s[1] = bfs(((const float*)&br[mat][1])[i]);
      s[2] = bfs(((const float*)&br[mat][2])[i]);
      s[3] = bfs(((const float*)&br[mat][3])[i]);
      *(short4v*)(bts[mat] + c2 * 128 + ((kb * 8) ^ ((c2 & 7) << 4))) = s;
    }
  }
}

__device__ __forceinline__ void write_bt1(char* bt, const float4 (&br)[4], int kb, int jb) {
  #pragma unroll
  for (int i = 0; i < 4; ++i) {
    int c2 = jb * 4 + i;
    short4v s;
    s[0] = bfs(((const float*)&br[0])[i]);
    s[1] = bfs(((const float*)&br[1])[i]);
    s[2] = bfs(((const float*)&br[2])[i]);
    s[3] = bfs(((const float*)&br[3])[i]);
    *(short4v*)(bt + c2 * 128 + ((kb * 8) ^ ((c2 & 7) << 4))) = s;
  }
}

// ---------------- GEMM1: H = silu(Xe Wg + bg) * (Xe Wi + bi) ----------------
// Pipelined: B(k+1)->regs + A(k+1)->LDS[alt] issued at iter top; raw s_barrier
// mid-iter (no vmcnt drain => prefetches stay in flight); __syncthreads at end.
__launch_bounds__(256, 3)
__global__ void gemm1_kernel(const short* __restrict__ Xe, const float* __restrict__ Wg,
                             const float* __restrict__ bg, const float* __restrict__ Wi,
                             const float* __restrict__ bi, const int* __restrict__ meta,
                             short* __restrict__ H) {
  int nt = meta[M_NTILES];
  int ty = blockIdx.y;
  if (ty >= nt) return;
  int e = meta[M_TE + ty], row0 = meta[M_TR + ty], rows = meta[M_TV + ty];
  int j0 = blockIdx.x * 64;
  __shared__ short As[2][128 * 64];   // double-buffered A, 32 KB
  __shared__ short Bt[2][64 * 64];    // [mat][col][k], single-buffered, 16 KB
  int tid = threadIdx.x;
  int lane = tid & 63, w = tid >> 6;
  int wm = w >> 1, wn = w & 1;        // 2x2 waves, wave tile 64x32
  int kb = tid & 15, jb = tid >> 4;   // B staging mapping (kb fast!)
  const float* W0 = Wg + (size_t)e * DIM * HID;
  const float* W1 = Wi + (size_t)e * DIM * HID;
  f32x4 ag[4][2] = {};
  f32x4 av[4][2] = {};
  float4 br[2][4];

  // ---- prologue: B(0)->regs (first!), A(0)->LDS, write Bt(0) ----
  #pragma unroll
  for (int mat = 0; mat < 2; ++mat) {
    const float* base = (mat ? W1 : W0) + (size_t)(kb * 4) * HID + j0 + jb * 4;
    #pragma unroll
    for (int r = 0; r < 4; ++r) br[mat][r] = *(const float4*)(base + r * HID);
  }
  #pragma unroll
  for (int q = 0; q < 4; ++q) {
    const char* src = (const char*)Xe + (size_t)(row0 + (w * 4 + q) * 8 + (lane >> 3)) * (DIM * 2)
                      + (lane & 7) * 16;
    __builtin_amdgcn_global_load_lds((const __attribute__((address_space(1))) void*)src,
                                     (__attribute__((address_space(3))) void*)((char*)&As[0][0] + (w * 4 + q) * 1024),
                                     16, 0, 0);
  }
  write_bt2((char*)&Bt[0][0], (char*)&Bt[1][0], br, kb, jb);
  __syncthreads();

  int cur = 0;
  for (int kt = 0; kt < 12; ++kt) {
    if (kt < 11) {
      // prefetch B(kt+1) into regs (issued first => counted vmcnt at use)
      #pragma unroll
      for (int mat = 0; mat < 2; ++mat) {
        const float* base = (mat ? W1 : W0) + (size_t)((kt + 1) * 64 + kb * 4) * HID + j0 + jb * 4;
        #pragma unroll
        for (int r = 0; r < 4; ++r) br[mat][r] = *(const float4*)(base + r * HID);
      }
      // prefetch A(kt+1) into alt LDS buffer
      #pragma unroll
      for (int q = 0; q < 4; ++q) {
        const char* src = (const char*)Xe + (size_t)(row0 + (w * 4 + q) * 8 + (lane >> 3)) * (DIM * 2)
                          + (kt + 1) * 128 + (lane & 7) * 16;
        __builtin_amdgcn_global_load_lds((const __attribute__((address_space(1))) void*)src,
                                         (__attribute__((address_space(3))) void*)((char*)&As[cur ^ 1][0] + (w * 4 + q) * 1024),
                                         16, 0, 0);
      }
    }
    // ---- compute on As[cur], Bt ----
    #pragma unroll
    for (int kf = 0; kf < 2; ++kf) {
      short8 af[4];
      #pragma unroll
      for (int m = 0; m < 4; ++m) {
        int r = wm * 64 + m * 16 + (lane & 15);
        int coff = (kf * 64 + (lane >> 4) * 16) ^ ((r & 7) << 4);
        af[m] = *(const short8*)((const char*)&As[cur][0] + r * 128 + coff);
      }
      #pragma unroll
      for (int n = 0; n < 2; ++n) {
        int c = wn * 32 + n * 16 + (lane & 15);
        int coff = (kf * 64 + (lane >> 4) * 16) ^ ((c & 7) << 4);
        short8 b0 = *(const short8*)((const char*)&Bt[0][0] + c * 128 + coff);
        short8 b1 = *(const short8*)((const char*)&Bt[1][0] + c * 128 + coff);
        #pragma unroll
        for (int m = 0; m < 4; ++m) {
          ag[m][n] = __builtin_amdgcn_mfma_f32_16x16x32_bf16(af[m], b0, ag[m][n], 0, 0, 0);
          av[m][n] = __builtin_amdgcn_mfma_f32_16x16x32_bf16(af[m], b1, av[m][n], 0, 0, 0);
        }
      }
    }
    // barrier 1: LDS reads done; NO vmcnt drain (prefetches stay in flight)
    asm volatile("s_waitcnt lgkmcnt(0)\n\ts_barrier" ::: "memory");
    if (kt < 11) write_bt2((char*)&Bt[0][0], (char*)&Bt[1][0], br, kb, jb);
    __syncthreads();   // barrier 2: Bt writes + A-gloads (had a full iter in flight)
    cur ^= 1;
  }

  // ---- epilogue: bias + silu*v, write H (bf16, pre-swizzled) ----
  #pragma unroll
  for (int n = 0; n < 2; ++n) {
    int c = j0 + wn * 32 + n * 16 + (lane & 15);
    float bgv = bg[e * HID + c];
    float biv = bi[e * HID + c];
    #pragma unroll
    for (int m = 0; m < 4; ++m) {
      #pragma unroll
      for (int r = 0; r < 4; ++r) {
        int rl = wm * 64 + m * 16 + (lane >> 4) * 4 + r;
        if (rl < rows) {
          float g = ag[m][n][r] + bgv;
          float v = av[m][n][r] + biv;
          float h = g / (1.f + __expf(-g)) * v;
          int grow = row0 + rl;
          int off = grow * (HID * 2) + (c >> 6) * 128 + ((2 * (c & 63)) ^ ((grow & 7) << 4));
          *(short*)((char*)H + off) = bfs(h);
        }
      }
    }
  }
}

// ---------------- GEMM2: out[perm] = H Wo + bo ----------------
__launch_bounds__(256, 3)
__global__ void gemm2_kernel(const short* __restrict__ H, const float* __restrict__ Wo,
                             const float* __restrict__ bo, const int* __restrict__ meta,
                             float* __restrict__ out) {
  int nt = meta[M_NTILES];
  int ty = blockIdx.y;
  if (ty >= nt) return;
  int e = meta[M_TE + ty], row0 = meta[M_TR + ty], rows = meta[M_TV + ty];
  int j0 = blockIdx.x * 64;
  __shared__ short As[2][128 * 64];   // 32 KB
  __shared__ short Bt[64 * 64];       // 8 KB
  int tid = threadIdx.x;
  int lane = tid & 63, w = tid >> 6;
  int wm = w >> 1, wn = w & 1;
  int kb = tid & 15, jb = tid >> 4;
  const float* W2 = Wo + (size_t)e * HID * DIM;
  f32x4 acc[4][2] = {};
  float4 br[4];

  #pragma unroll
  for (int r = 0; r < 4; ++r)
    br[r] = *(const float4*)(W2 + (size_t)(kb * 4 + r) * DIM + j0 + jb * 4);
  #pragma unroll
  for (int q = 0; q < 4; ++q) {
    const char* src = (const char*)H + (size_t)(row0 + (w * 4 + q) * 8 + (lane >> 3)) * (HID * 2)
                      + (lane & 7) * 16;
    __builtin_amdgcn_global_load_lds((const __attribute__((address_space(1))) void*)src,
                                     (__attribute__((address_space(3))) void*)((char*)&As[0][0] + (w * 4 + q) * 1024),
                                     16, 0, 0);
  }
  write_bt1((char*)&Bt[0], br, kb, jb);
  __syncthreads();

  int cur = 0;
  for (int kt = 0; kt < 48; ++kt) {
    if (kt < 47) {
      #pragma unroll
      for (int r = 0; r < 4; ++r)
        br[r] = *(const float4*)(W2 + (size_t)((kt + 1) * 64 + kb * 4 + r) * DIM + j0 + jb * 4);
      #pragma unroll
      for (int q = 0; q < 4; ++q) {
        const char* src = (const char*)H + (size_t)(row0 + (w * 4 + q) * 8 + (lane >> 3)) * (HID * 2)
                          + (kt + 1) * 128 + (lane & 7) * 16;
        __builtin_amdgcn_global_load_lds((const __attribute__((address_space(1))) void*)src,
                                         (__attribute__((address_space(3))) void*)((char*)&As[cur ^ 1][0] + (w * 4 + q) * 1024),
                                         16, 0, 0);
      }
    }
    #pragma unroll
    for (int kf = 0; kf < 2; ++kf) {
      short8 af[4];
      #pragma unroll
      for (int m = 0; m < 4; ++m) {
        int r = wm * 64 + m * 16 + (lane & 15);
        int coff = (kf * 64 + (lane >> 4) * 16) ^ ((r & 7) << 4);
        af[m] = *(const short8*)((const char*)&As[cur][0] + r * 128 + coff);
      }
      #pragma unroll
      for (int n = 0; n < 2; ++n) {
        int c = wn * 32 + n * 16 + (lane & 15);
        int coff = (kf * 64 + (lane >> 4) * 16) ^ ((c & 7) << 4);
        short8 b0 = *(const short8*)((const char*)&Bt[0] + c * 128 + coff);
        #pragma unroll
        for (int m = 0; m < 4; ++m) {
          acc[m][n] = __builtin_amdgcn_mfma_f32_16x16x32_bf16(af[m], b0, acc[m][n], 0, 0, 0);
        }
      }
    }
    asm volatile("s_waitcnt lgkmcnt(0)\n\ts_barrier" ::: "memory");
    if (kt < 47) write_bt1((char*)&Bt[0], br, kb, jb);
    __syncthreads();
    cur ^= 1;
  }

  #pragma unroll
  for (int n = 0; n < 2; ++n) {
    int c = j0 + wn * 32 + n * 16 + (lane & 15);
    float bov = bo[e * DIM + c];
    #pragma unroll
    for (int m = 0; m < 4; ++m) {
      #pragma unroll
      for (int r = 0; r < 4; ++r) {
        int rl = wm * 64 + m * 16 + (lane >> 4) * 4 + r;
        if (rl < rows) {
          int tok = meta[M_PERM + row0 + rl];
          out[(size_t)tok * DIM + c] = acc[m][n][r] + bov;
        }
      }
    }
  }
}

extern "C" void kernel_launch(void* const* d_in, const int* in_sizes, int n_in,
                              void* d_out, int out_size, void* d_ws, size_t ws_size,
                              hipStream_t stream) {
  (void)in_sizes; (void)n_in; (void)out_size; (void)ws_size;
  const float* x   = (const float*)d_in[0];
  const int*   map = (const int*)d_in[1];
  const float* Wg  = (const float*)d_in[2];
  const float* bg  = (const float*)d_in[3];
  const float* Wi  = (const float*)d_in[4];
  const float* bi  = (const float*)d_in[5];
  const float* Wo  = (const float*)d_in[6];
  const float* bo  = (const float*)d_in[7];
  float* out = (float*)d_out;
  int* meta = (int*)d_ws;
  short* Xe = (short*)((char*)d_ws + XE_OFF);
  short* H  = (short*)((char*)d_ws + H_OFF);

  hipLaunchKernelGGL(route_kernel, dim3(1), dim3(256), 0, stream, map, meta);
  hipLaunchKernelGGL(gather_kernel, dim3(PADROWS * 96 / 256), dim3(256), 0, stream, x, meta, Xe);
  hipLaunchKernelGGL(gemm1_kernel, dim3(HID / 64, MAXT), dim3(256), 0, stream,
                     Xe, Wg, bg, Wi, bi, meta, H);
  hipLaunchKernelGGL(gemm2_kernel, dim3(DIM / 64, MAXT), dim3(256), 0, stream,
                     H, Wo, bo, meta, out);
}